// Round 3
// baseline (175.957 us; speedup 1.0000x reference)
//
#include <hip/hip_runtime.h>
#include <hip/hip_bf16.h>
#include <stdint.h>

#define K_DIM 4096
#define N_DIM 11008
#define M_DIM 512
#define PK_ROW 5504          // int32 code-words per k-row (one per n-pair)
#define SC_ROW 172           // scale blocks per k-row
#define BM 128
#define BN 64
#define BK 64
#define NT (K_DIM / BK)      // 64 k-tiles

typedef __attribute__((ext_vector_type(8))) short bf16x8;
typedef __attribute__((ext_vector_type(4))) float f32x4;
typedef __attribute__((ext_vector_type(4))) int i32x4;
typedef __attribute__((ext_vector_type(4))) unsigned int u32x4;

__constant__ float NF4[16] = {
    -1.0f, -0.6961928009986877f, -0.5250730514526367f, -0.39491748809814453f,
    -0.28444138169288635f, -0.18477343022823334f, -0.09105003625154495f, 0.0f,
    0.07958029955625534f, 0.16093020141124725f, 0.24611230194568634f,
    0.33791524171829224f, 0.44070982933044434f, 0.5626170039176941f,
    0.7229568362236023f, 1.0f};

__device__ __forceinline__ unsigned f2bf(float v) {
  union { __hip_bfloat16 h; unsigned short u; } cv;
  cv.h = __float2bfloat16(v);
  return (unsigned)cv.u;
}

// ---- kernel 1: x fp32 -> bf16, MFMA-fragment-block layout in ws ----
// ws layout: block (m16, k32) = 1KB, addr = ((m16*128 + k32)*64 + lane)*16B
// lane l holds A[m16*16 + (l&15)][k32*32 + (l>>4)*8 .. +8)
__global__ __launch_bounds__(256) void conv_a(const float* __restrict__ x,
                                              unsigned short* __restrict__ wsa) {
  const int wid = blockIdx.x * 4 + (threadIdx.x >> 6);  // 4096 wave-tasks
  const int lane = threadIdx.x & 63;
  const int m16 = wid >> 7;   // 0..31
  const int k32 = wid & 127;  // 0..127
  const int m = m16 * 16 + (lane & 15);
  const int k = k32 * 32 + (lane >> 4) * 8;
  const float* src = x + (size_t)m * K_DIM + k;
  f32x4 v0 = *(const f32x4*)src;
  f32x4 v1 = *(const f32x4*)(src + 4);
  u32x4 d;
  d[0] = f2bf(v0[0]) | (f2bf(v0[1]) << 16);
  d[1] = f2bf(v0[2]) | (f2bf(v0[3]) << 16);
  d[2] = f2bf(v1[0]) | (f2bf(v1[1]) << 16);
  d[3] = f2bf(v1[2]) | (f2bf(v1[3]) << 16);
  *(u32x4*)(wsa + ((size_t)wid * 64 + lane) * 8) = d;
}

// ---- kernel 2: fused NF4-dequant GEMM ----
// 128x64 tile, 4 waves (2x2), wave tile 64x32, B double-buffered in LDS.
__global__ __launch_bounds__(256) void nf4_gemm(
    const int* __restrict__ packed, const float* __restrict__ scales,
    const float* __restrict__ bias, const unsigned short* __restrict__ wsa,
    float* __restrict__ out) {
  // B buffers: [n][swizzled 128B of 64 k bf16], byte ^= ((n&7)<<4)
  __shared__ __align__(16) char Bbuf0[BN * 128];
  __shared__ __align__(16) char Bbuf1[BN * 128];
  __shared__ float2 Lut[256];

  const int t = threadIdx.x;
  // XCD swizzle: 688 = 8*86 bijective; clusters one m-tile per XCD (A slice L2-res)
  const int bid = blockIdx.x;
  const int swz = (bid & 7) * 86 + (bid >> 3);
  const int m_tile = (swz / 172) * BM;
  const int n_tile = (swz % 172) * BN;

  Lut[t] = make_float2(NF4[(t >> 4) & 15], NF4[t & 15]);

  const int lane = t & 63;
  const int wid = t >> 6;
  const int wm = (wid >> 1) * 64;
  const int wn = (wid & 1) * 32;
  const int l15 = lane & 15;
  const int l4 = lane >> 4;
  const int m16w = (m_tile >> 4) + (wid >> 1) * 4;  // wave's first m16 block

  // B staging: thread owns k-pair (2*kp, 2*kp+1) x n-octet noct*8..+7
  const int kp = t & 31;
  const int noct = t >> 5;
  const size_t pk_base = (size_t)(n_tile >> 1) + noct * 4;
  const int sc_col = n_tile >> 6;

  f32x4 acc[4][2];
#pragma unroll
  for (int i = 0; i < 4; ++i) {
    acc[i][0] = (f32x4){0.f, 0.f, 0.f, 0.f};
    acc[i][1] = (f32x4){0.f, 0.f, 0.f, 0.f};
  }

  i32x4 ga0, gb0, ga1, gb1;  // raw codes: (set0, set1) x (row k, row k+1)
  float s0a, s0b, s1a, s1b;
  bf16x8 a0[8], a1[8];

  auto loadB0 = [&](int tau) {
    const size_t kb = (size_t)tau * BK + 2 * kp;
    ga0 = *(const i32x4*)(packed + kb * PK_ROW + pk_base);
    gb0 = *(const i32x4*)(packed + (kb + 1) * PK_ROW + pk_base);
    s0a = scales[kb * SC_ROW + sc_col];
    s0b = scales[(kb + 1) * SC_ROW + sc_col];
  };
  auto loadB1 = [&](int tau) {
    const size_t kb = (size_t)tau * BK + 2 * kp;
    ga1 = *(const i32x4*)(packed + kb * PK_ROW + pk_base);
    gb1 = *(const i32x4*)(packed + (kb + 1) * PK_ROW + pk_base);
    s1a = scales[kb * SC_ROW + sc_col];
    s1b = scales[(kb + 1) * SC_ROW + sc_col];
  };
  auto dequant = [&](const i32x4& wa, const i32x4& wb, float sa, float sb,
                     char* buf) {
#pragma unroll
    for (int e = 0; e < 4; ++e) {
      const float2 p0 = Lut[wa[e] & 255];
      const float2 p1 = Lut[wb[e] & 255];
      const int n0 = noct * 8 + 2 * e;
      const unsigned v0 = f2bf(p0.x * sa) | (f2bf(p1.x * sb) << 16);
      *(unsigned*)(buf + n0 * 128 + ((4 * kp) ^ ((n0 & 7) << 4))) = v0;
      const int n1 = n0 + 1;
      const unsigned v1 = f2bf(p0.y * sa) | (f2bf(p1.y * sb) << 16);
      *(unsigned*)(buf + n1 * 128 + ((4 * kp) ^ ((n1 & 7) << 4))) = v1;
    }
  };
  auto loadA = [&](bf16x8* A, int tau) {
    const int k32 = tau * 2;
#pragma unroll
    for (int fm = 0; fm < 4; ++fm)
#pragma unroll
      for (int ks = 0; ks < 2; ++ks)
        A[fm * 2 + ks] = *(const bf16x8*)(wsa +
            (((size_t)(m16w + fm) * 128 + k32 + ks) * 64 + lane) * 8);
  };
  auto compute = [&](const char* buf, const bf16x8* A) {
    bf16x8 bf[2][2];
#pragma unroll
    for (int fn = 0; fn < 2; ++fn) {
      const int n = wn + fn * 16 + l15;
#pragma unroll
      for (int ks = 0; ks < 2; ++ks)
        bf[fn][ks] = *(const bf16x8*)(buf + n * 128 +
                                      ((ks * 64 + l4 * 16) ^ ((n & 7) << 4)));
    }
#pragma unroll
    for (int fm = 0; fm < 4; ++fm)
#pragma unroll
      for (int fn = 0; fn < 2; ++fn) {
        acc[fm][fn] = __builtin_amdgcn_mfma_f32_16x16x32_bf16(
            A[fm * 2 + 0], bf[fn][0], acc[fm][fn], 0, 0, 0);
        acc[fm][fn] = __builtin_amdgcn_mfma_f32_16x16x32_bf16(
            A[fm * 2 + 1], bf[fn][1], acc[fm][fn], 0, 0, 0);
      }
  };

  // prologue
  loadB0(0);
  loadB1(1);
  loadA(a0, 0);
  loadA(a1, 1);
  __syncthreads();  // Lut visible
  dequant(ga0, gb0, s0a, s0b, Bbuf0);
  loadB0(2);
  __syncthreads();  // Bbuf0 ready

#pragma unroll 1
  for (int tt = 0; tt < NT / 2; ++tt) {
    // even tile 2tt: compute Bbuf0/a0; stage tile 2tt+1 -> Bbuf1
    dequant(ga1, gb1, s1a, s1b, Bbuf1);
    if (tt < NT / 2 - 1) loadB1(2 * tt + 3);
    compute(Bbuf0, a0);
    if (tt < NT / 2 - 1) loadA(a0, 2 * tt + 2);
    __syncthreads();  // Bbuf1 ready, Bbuf0 free
    // odd tile 2tt+1: compute Bbuf1/a1; stage tile 2tt+2 -> Bbuf0
    if (tt < NT / 2 - 1) {
      dequant(ga0, gb0, s0a, s0b, Bbuf0);
      // FIX(R2 crash): tile 2*tt+4 only exists while tt+1 has an odd-phase
      // dequant, i.e. tt < NT/2-2. Old guard issued loadB0(64) at tt=30 ->
      // OOB read ~1.4MB past `packed` -> core dump.
      if (tt < NT / 2 - 2) loadB0(2 * tt + 4);
    }
    compute(Bbuf1, a1);
    if (tt < NT / 2 - 1) loadA(a1, 2 * tt + 3);
    __syncthreads();  // Bbuf0 ready, Bbuf1 free
  }

  // epilogue
#pragma unroll
  for (int fn = 0; fn < 2; ++fn) {
    const int gc = n_tile + wn + fn * 16 + l15;
    const float bi = bias[gc];
#pragma unroll
    for (int fm = 0; fm < 4; ++fm) {
#pragma unroll
      for (int r = 0; r < 4; ++r) {
        const int gr = m_tile + wm + fm * 16 + l4 * 4 + r;
        out[(size_t)gr * N_DIM + gc] = acc[fm][fn][r] + bi;
      }
    }
  }
}

// ---- fallback (round-1 kernel, passes at 155us): used only if ws too small ----
#define FLDS 72
__global__ __launch_bounds__(256) void nf4_gemm_fused(
    const float* __restrict__ x, const int* __restrict__ packed,
    const float* __restrict__ scales, const float* __restrict__ bias,
    float* __restrict__ out) {
  __shared__ unsigned short Alds[128 * FLDS];
  __shared__ unsigned short Blds[128 * FLDS];
  __shared__ float2 Lut[256];
  const int t = threadIdx.x;
  const int bid = blockIdx.x;
  const int swz = (bid & 7) * 43 + (bid >> 3);
  const int m_tile = (swz / 86) * 128;
  const int n_tile = (swz % 86) * 128;
  Lut[t] = make_float2(NF4[(t >> 4) & 15], NF4[t & 15]);
  const int lane = t & 63;
  const int wid = t >> 6;
  const int wm = (wid >> 1) * 64;
  const int wn = (wid & 1) * 64;
  const int l15 = lane & 15;
  const int l4 = lane >> 4;
  f32x4 acc[4][4];
#pragma unroll
  for (int i = 0; i < 4; ++i)
#pragma unroll
    for (int j = 0; j < 4; ++j) acc[i][j] = (f32x4){0.f, 0.f, 0.f, 0.f};
  const int mlane = t & 15;
  const int n_sub = mlane * 8;
  const int k_sub = 4 * (((t >> 4) + mlane) & 15);
  const int c4 = t & 15;
  const int r0 = t >> 4;
  for (int k0 = 0; k0 < K_DIM; k0 += 64) {
    __syncthreads();
#pragma unroll
    for (int i = 0; i < 8; ++i) {
      const int row = r0 + 16 * i;
      f32x4 xv = *(const f32x4*)(x + (size_t)(m_tile + row) * K_DIM + k0 + c4 * 4);
      uint2 d;
      d.x = f2bf(xv[0]) | (f2bf(xv[1]) << 16);
      d.y = f2bf(xv[2]) | (f2bf(xv[3]) << 16);
      *(uint2*)(&Alds[row * FLDS + c4 * 4]) = d;
    }
    {
      const int* pk = packed + (size_t)(k0 + k_sub) * PK_ROW + ((n_tile + n_sub) >> 1);
      i32x4 w[4];
      float s[4];
#pragma unroll
      for (int kk = 0; kk < 4; ++kk) {
        w[kk] = *(const i32x4*)(pk + (size_t)kk * PK_ROW);
        s[kk] = scales[(size_t)(k0 + k_sub + kk) * SC_ROW + ((n_tile + n_sub) >> 6)];
      }
      float v[4][8];
#pragma unroll
      for (int kk = 0; kk < 4; ++kk)
#pragma unroll
        for (int e = 0; e < 4; ++e) {
          const int b = w[kk][e] & 0xFF;
          const float2 p = Lut[b];
          v[kk][2 * e] = p.x * s[kk];
          v[kk][2 * e + 1] = p.y * s[kk];
        }
#pragma unroll
      for (int j = 0; j < 8; ++j) {
        uint2 d;
        d.x = f2bf(v[0][j]) | (f2bf(v[1][j]) << 16);
        d.y = f2bf(v[2][j]) | (f2bf(v[3][j]) << 16);
        *(uint2*)(&Blds[(n_sub + j) * FLDS + k_sub]) = d;
      }
    }
    __syncthreads();
#pragma unroll
    for (int ks = 0; ks < 2; ++ks) {
      bf16x8 af[4], bfv[4];
#pragma unroll
      for (int fm = 0; fm < 4; ++fm)
        af[fm] = *(const bf16x8*)(&Alds[(wm + fm * 16 + l15) * FLDS + ks * 32 + l4 * 8]);
#pragma unroll
      for (int fn = 0; fn < 4; ++fn)
        bfv[fn] = *(const bf16x8*)(&Blds[(wn + fn * 16 + l15) * FLDS + ks * 32 + l4 * 8]);
#pragma unroll
      for (int fm = 0; fm < 4; ++fm)
#pragma unroll
        for (int fn = 0; fn < 4; ++fn)
          acc[fm][fn] = __builtin_amdgcn_mfma_f32_16x16x32_bf16(af[fm], bfv[fn], acc[fm][fn], 0, 0, 0);
    }
  }
#pragma unroll
  for (int fn = 0; fn < 4; ++fn) {
    const float bi = bias[n_tile + wn + fn * 16 + l15];
#pragma unroll
    for (int fm = 0; fm < 4; ++fm)
#pragma unroll
      for (int r = 0; r < 4; ++r) {
        const int gr = m_tile + wm + fm * 16 + l4 * 4 + r;
        out[(size_t)gr * N_DIM + n_tile + wn + fn * 16 + l15] = acc[fm][fn][r] + bi;
      }
  }
}

extern "C" void kernel_launch(void* const* d_in, const int* in_sizes, int n_in,
                              void* d_out, int out_size, void* d_ws, size_t ws_size,
                              hipStream_t stream) {
  const float* x = (const float*)d_in[0];
  const int* packed = (const int*)d_in[1];
  const float* scales = (const float*)d_in[2];
  const float* bias = (const float*)d_in[3];
  float* out = (float*)d_out;

  const size_t need = (size_t)M_DIM * K_DIM * 2;  // 4MB bf16 A copy
  if (ws_size >= need) {
    unsigned short* wsa = (unsigned short*)d_ws;
    conv_a<<<dim3(1024), dim3(256), 0, stream>>>(x, wsa);
    nf4_gemm<<<dim3(688), dim3(256), 0, stream>>>(packed, scales, bias, wsa, out);
  } else {
    nf4_gemm_fused<<<dim3(344), dim3(256), 0, stream>>>(x, packed, scales, bias, out);
  }
}